// Round 1
// baseline (1987.808 us; speedup 1.0000x reference)
//
#include <hip/hip_runtime.h>

// Problem constants (from reference): x[8192][4096] fp32, U[4096][64], V[4096][64], bias[4096]
// out[m][o] = bias[o] + sum_r ( sum_i x[m][i] * V[i][r] ) * U[o][r]
#define IN_F    4096
#define OUT_F   4096
#define RANK    64
#define M_TOTAL 8192
#define M_TILE  16
#define K_TILE  128
#define O_CHUNK 1024   // 256 threads * 4 outputs

__global__ __launch_bounds__(256, 4) void fused_lowrank_linear(
    const float* __restrict__ x, const float* __restrict__ U,
    const float* __restrict__ V, const float* __restrict__ bias,
    float* __restrict__ out)
{
    __shared__ float v_lds[K_TILE][RANK];   // 32 KB, V k-tile
    __shared__ float t_lds[M_TILE][RANK];   // 4 KB, intermediate t = x @ V

    const int tid  = threadIdx.x;
    const int lane = tid & 63;   // r index in phase 1
    const int wave = tid >> 6;   // 0..3
    const int m0   = blockIdx.x * M_TILE;

    // ---------------- Phase 1: t[m][r] = sum_k x[m][k] * V[k][r] ----------------
    // Each wave handles 4 rows; lane = r. x loads are wave-uniform float4 broadcasts.
    float acc0 = 0.f, acc1 = 0.f, acc2 = 0.f, acc3 = 0.f;
    const size_t row_base = (size_t)(m0 + wave * 4) * IN_F;

    for (int kt = 0; kt < IN_F; kt += K_TILE) {
        // Stage V tile: K_TILE*RANK = 8192 floats = 2048 float4, 8 per thread.
        {
            const float4* Vg = (const float4*)(V + (size_t)kt * RANK);
            float4* Vs = (float4*)(&v_lds[0][0]);
            #pragma unroll
            for (int i = 0; i < 8; ++i)
                Vs[tid + 256 * i] = Vg[tid + 256 * i];
        }
        __syncthreads();

        const float* xp = x + row_base + kt;
        #pragma unroll 8
        for (int k = 0; k < K_TILE; k += 4) {
            float v0 = v_lds[k + 0][lane];
            float v1 = v_lds[k + 1][lane];
            float v2 = v_lds[k + 2][lane];
            float v3 = v_lds[k + 3][lane];
            float4 xa = *(const float4*)(xp + 0 * IN_F + k);
            float4 xb = *(const float4*)(xp + 1 * IN_F + k);
            float4 xc = *(const float4*)(xp + 2 * IN_F + k);
            float4 xd = *(const float4*)(xp + 3 * IN_F + k);
            acc0 += xa.x * v0 + xa.y * v1 + xa.z * v2 + xa.w * v3;
            acc1 += xb.x * v0 + xb.y * v1 + xb.z * v2 + xb.w * v3;
            acc2 += xc.x * v0 + xc.y * v1 + xc.z * v2 + xc.w * v3;
            acc3 += xd.x * v0 + xd.y * v1 + xd.z * v2 + xd.w * v3;
        }
        __syncthreads();
    }
    t_lds[wave * 4 + 0][lane] = acc0;
    t_lds[wave * 4 + 1][lane] = acc1;
    t_lds[wave * 4 + 2][lane] = acc2;
    t_lds[wave * 4 + 3][lane] = acc3;
    __syncthreads();

    // ---------------- Phase 2: out[m][o] = bias[o] + sum_r t[m][r] * U[o][r] ----------------
    // Thread owns 4 consecutive o (float4) x 16 m. t read as uniform ds_read_b128 broadcast,
    // U read as per-lane contiguous float4 (L2-resident).
    for (int oc = 0; oc < OUT_F; oc += O_CHUNK) {
        const int o4 = oc + tid * 4;
        const float4 b4 = *(const float4*)(bias + o4);
        float4 acc[M_TILE];
        #pragma unroll
        for (int m = 0; m < M_TILE; ++m) acc[m] = b4;

        for (int r0 = 0; r0 < RANK; r0 += 4) {
            const float4 u0 = *(const float4*)(U + (size_t)(o4 + 0) * RANK + r0);
            const float4 u1 = *(const float4*)(U + (size_t)(o4 + 1) * RANK + r0);
            const float4 u2 = *(const float4*)(U + (size_t)(o4 + 2) * RANK + r0);
            const float4 u3 = *(const float4*)(U + (size_t)(o4 + 3) * RANK + r0);
            #pragma unroll
            for (int m = 0; m < M_TILE; ++m) {
                const float4 t4 = *(const float4*)(&t_lds[m][r0]);
                acc[m].x += t4.x * u0.x + t4.y * u0.y + t4.z * u0.z + t4.w * u0.w;
                acc[m].y += t4.x * u1.x + t4.y * u1.y + t4.z * u1.z + t4.w * u1.w;
                acc[m].z += t4.x * u2.x + t4.y * u2.y + t4.z * u2.z + t4.w * u2.w;
                acc[m].w += t4.x * u3.x + t4.y * u3.y + t4.z * u3.z + t4.w * u3.w;
            }
        }
        #pragma unroll
        for (int m = 0; m < M_TILE; ++m)
            *(float4*)(out + (size_t)(m0 + m) * OUT_F + o4) = acc[m];
    }
}

extern "C" void kernel_launch(void* const* d_in, const int* in_sizes, int n_in,
                              void* d_out, int out_size, void* d_ws, size_t ws_size,
                              hipStream_t stream) {
    const float* x    = (const float*)d_in[0];
    const float* U    = (const float*)d_in[1];
    const float* V    = (const float*)d_in[2];
    const float* bias = (const float*)d_in[3];
    float* out = (float*)d_out;

    dim3 grid(M_TOTAL / M_TILE);   // 512 blocks
    dim3 block(256);
    fused_lowrank_linear<<<grid, block, 0, stream>>>(x, U, V, bias, out);
}

// Round 2
// 673.782 us; speedup vs baseline: 2.9502x; 2.9502x over previous
//
#include <hip/hip_runtime.h>

// out[m][o] = bias[o] + sum_r ( sum_i x[m][i] * V[i][r] ) * U[o][r]
// x[8192][4096] fp32, U[4096][64], V[4096][64], bias[4096]
#define IN_F    4096
#define OUT_F   4096
#define RANK    64
#define M_TOTAL 8192
#define M_TILE  8      // rows per block -> 1024 blocks = 4 blocks/CU
#define K_TILE  128

__global__ __launch_bounds__(256, 2) void fused_lowrank_linear(
    const float* __restrict__ x, const float* __restrict__ U,
    const float* __restrict__ V, const float* __restrict__ bias,
    float* __restrict__ out)
{
    __shared__ float v_lds[K_TILE][RANK];   // 32 KB: V k-tile
    __shared__ float t_lds[M_TILE][RANK];   // 2 KB:  t = x @ V for this block's rows

    const int tid  = threadIdx.x;
    const int lane = tid & 63;   // r index in phase 1
    const int wave = tid >> 6;   // 0..3
    const int m0   = blockIdx.x * M_TILE;

    // ---------------- Phase 1: t[m][r] = sum_k x[m][k] * V[k][r] ----------------
    // wave handles 2 rows; lane = r. x loads are wave-uniform float4 (scalar-load friendly).
    float acc0 = 0.f, acc1 = 0.f;
    const size_t row_base = (size_t)(m0 + wave * 2) * IN_F;

    for (int kt = 0; kt < IN_F; kt += K_TILE) {
        {   // stage V tile: 8192 floats = 2048 float4, 8 per thread, coalesced
            const float4* Vg = (const float4*)(V + (size_t)kt * RANK);
            float4* Vs = (float4*)(&v_lds[0][0]);
            #pragma unroll
            for (int i = 0; i < 8; ++i)
                Vs[tid + 256 * i] = Vg[tid + 256 * i];
        }
        __syncthreads();

        const float* xp = x + row_base + kt;
        #pragma unroll 8
        for (int k = 0; k < K_TILE; k += 4) {
            float v0 = v_lds[k + 0][lane];
            float v1 = v_lds[k + 1][lane];
            float v2 = v_lds[k + 2][lane];
            float v3 = v_lds[k + 3][lane];
            float4 xa = *(const float4*)(xp + 0 * IN_F + k);
            float4 xb = *(const float4*)(xp + 1 * IN_F + k);
            acc0 += xa.x * v0 + xa.y * v1 + xa.z * v2 + xa.w * v3;
            acc1 += xb.x * v0 + xb.y * v1 + xb.z * v2 + xb.w * v3;
        }
        __syncthreads();
    }
    t_lds[wave * 2 + 0][lane] = acc0;
    t_lds[wave * 2 + 1][lane] = acc1;
    __syncthreads();

    // ---------------- Phase 2: out[m][o] = bias[o] + sum_r t[m][r] * U[o][r] ----------------
    // Thread owns 4 consecutive o x 8 m. NAMED accumulators (32 VGPRs) -> no scratch array.
    // t reads are same-address LDS broadcasts; U reads are per-lane contiguous float4 (L2-hot).
    for (int oc = 0; oc < OUT_F; oc += 1024) {
        const int o4 = oc + tid * 4;
        const float4 b4 = *(const float4*)(bias + o4);
        float4 a0 = b4, a1 = b4, a2 = b4, a3 = b4, a4 = b4, a5 = b4, a6 = b4, a7 = b4;

        const float* Up = U + (size_t)o4 * RANK;

        #pragma unroll 2
        for (int r0 = 0; r0 < RANK; r0 += 4) {
            const float4 u0 = *(const float4*)(Up + 0 * RANK + r0);
            const float4 u1 = *(const float4*)(Up + 1 * RANK + r0);
            const float4 u2 = *(const float4*)(Up + 2 * RANK + r0);
            const float4 u3 = *(const float4*)(Up + 3 * RANK + r0);
            #define P2_STEP(AM, MM)                                              \
            {                                                                    \
                const float4 t4 = *(const float4*)(&t_lds[MM][r0]);              \
                AM.x += t4.x * u0.x + t4.y * u0.y + t4.z * u0.z + t4.w * u0.w;   \
                AM.y += t4.x * u1.x + t4.y * u1.y + t4.z * u1.z + t4.w * u1.w;   \
                AM.z += t4.x * u2.x + t4.y * u2.y + t4.z * u2.z + t4.w * u2.w;   \
                AM.w += t4.x * u3.x + t4.y * u3.y + t4.z * u3.z + t4.w * u3.w;   \
            }
            P2_STEP(a0, 0) P2_STEP(a1, 1) P2_STEP(a2, 2) P2_STEP(a3, 3)
            P2_STEP(a4, 4) P2_STEP(a5, 5) P2_STEP(a6, 6) P2_STEP(a7, 7)
            #undef P2_STEP
        }

        float* op = out + (size_t)m0 * OUT_F + o4;
        *(float4*)(op + 0 * OUT_F) = a0;
        *(float4*)(op + 1 * OUT_F) = a1;
        *(float4*)(op + 2 * OUT_F) = a2;
        *(float4*)(op + 3 * OUT_F) = a3;
        *(float4*)(op + 4 * OUT_F) = a4;
        *(float4*)(op + 5 * OUT_F) = a5;
        *(float4*)(op + 6 * OUT_F) = a6;
        *(float4*)(op + 7 * OUT_F) = a7;
    }
}

extern "C" void kernel_launch(void* const* d_in, const int* in_sizes, int n_in,
                              void* d_out, int out_size, void* d_ws, size_t ws_size,
                              hipStream_t stream) {
    const float* x    = (const float*)d_in[0];
    const float* U    = (const float*)d_in[1];
    const float* V    = (const float*)d_in[2];
    const float* bias = (const float*)d_in[3];
    float* out = (float*)d_out;

    dim3 grid(M_TOTAL / M_TILE);   // 1024 blocks
    dim3 block(256);
    fused_lowrank_linear<<<grid, block, 0, stream>>>(x, U, V, bias, out);
}

// Round 3
// 349.004 us; speedup vs baseline: 5.6957x; 1.9306x over previous
//
#include <hip/hip_runtime.h>

// out[m][o] = bias[o] + sum_r t[m][r]*U[o][r],  t[m][r] = sum_k x[m][k]*V[k][r]
// x[8192][4096] fp32, U[4096][64], V[4096][64], bias[4096]
#define IN_F    4096
#define OUT_F   4096
#define RANK    64
#define M_TOTAL 8192
#define M_TILE  16
#define BLOCK   512
#define NWAVES  8

using short8  = __attribute__((ext_vector_type(8))) short;
using float4v = __attribute__((ext_vector_type(4))) float;

#define MFMA16(A, B, C) __builtin_amdgcn_mfma_f32_16x16x32_bf16((A), (B), (C), 0, 0, 0)

// Exact split: x = f32(hi) + r, lo = trunc_bf16(r). Error of (hi,lo) pair ~2^-16 rel.
__device__ __forceinline__ void split2(float x, short& h, short& l) {
    unsigned u = __float_as_uint(x);
    unsigned t = u & 0xffff0000u;
    h = (short)(t >> 16);
    float r = x - __uint_as_float(t);
    l = (short)(__float_as_uint(r) >> 16);
}

__device__ __forceinline__ void split_f4x2(float4 a, float4 b, short8& hi, short8& lo) {
    short h0,h1,h2,h3,h4,h5,h6,h7, l0,l1,l2,l3,l4,l5,l6,l7;
    split2(a.x,h0,l0); split2(a.y,h1,l1); split2(a.z,h2,l2); split2(a.w,h3,l3);
    split2(b.x,h4,l4); split2(b.y,h5,l5); split2(b.z,h6,l6); split2(b.w,h7,l7);
    hi = (short8){h0,h1,h2,h3,h4,h5,h6,h7};
    lo = (short8){l0,l1,l2,l3,l4,l5,l6,l7};
}

// V[k][r] fp32 -> V_t_hi/lo[r][k] bf16 (transposed so phase-1 B-frags are contiguous 16B loads)
__global__ void prep_v(const float* __restrict__ V, unsigned short* __restrict__ vt_hi,
                       unsigned short* __restrict__ vt_lo) {
    int linear = blockIdx.x * 256 + threadIdx.x;   // 65536 threads
    int r  = linear >> 10;                          // 0..63
    int k0 = (linear & 1023) * 4;                   // 0..4092
    short h[4], l[4];
    #pragma unroll
    for (int i = 0; i < 4; ++i)
        split2(V[(size_t)(k0 + i) * RANK + r], h[i], l[i]);
    size_t o = (size_t)r * IN_F + k0;
    *(ushort4*)(vt_hi + o) = make_ushort4((unsigned short)h[0], (unsigned short)h[1],
                                          (unsigned short)h[2], (unsigned short)h[3]);
    *(ushort4*)(vt_lo + o) = make_ushort4((unsigned short)l[0], (unsigned short)l[1],
                                          (unsigned short)l[2], (unsigned short)l[3]);
}

__global__ __launch_bounds__(BLOCK, 4) void fused_lowrank_mfma(
    const float* __restrict__ x, const float* __restrict__ U,
    const float* __restrict__ bias, const unsigned short* __restrict__ vt_hi,
    const unsigned short* __restrict__ vt_lo, float* __restrict__ out)
{
    __shared__ float part[NWAVES][M_TILE][RANK + 4];       // 34816 B, fp32 t-partials
    __shared__ unsigned short t_hi[M_TILE][RANK + 8];      // 2304 B (pad -> conflict-free b128)
    __shared__ unsigned short t_lo[M_TILE][RANK + 8];

    const int tid  = threadIdx.x;
    const int wv   = tid >> 6;     // 0..7
    const int lane = tid & 63;
    const int l15  = lane & 15;
    const int quad = lane >> 4;    // 0..3
    const int m0   = blockIdx.x * M_TILE;

    // ---------- Phase 1: t[m][r] = sum_k x[m][k]*V[k][r], MFMA 16x16x32, K split over 8 waves ----------
    // A-frag: A[m=lane&15][k=quad*8+j] -> per-lane 2x float4 from x (coalesced 128B runs per row)
    // B-frag: B[k=quad*8+j][n=lane&15] -> per-lane 16B contiguous from vt_hi/lo[r][k]
    float4v acc[4] = {};   // 4 r-tiles of 16 cols
    const float*          xp = x     + (size_t)(m0 + l15) * IN_F + quad * 8;
    const unsigned short* vh = vt_hi + (size_t)l15 * IN_F + quad * 8;
    const unsigned short* vl = vt_lo + (size_t)l15 * IN_F + quad * 8;

    #pragma unroll 2
    for (int ks = 0; ks < 16; ++ks) {
        const int k0 = wv * 512 + ks * 32;
        float4 xa = *(const float4*)(xp + k0);
        float4 xb = *(const float4*)(xp + k0 + 4);
        short8 a_hi, a_lo;
        split_f4x2(xa, xb, a_hi, a_lo);
        #pragma unroll
        for (int rt = 0; rt < 4; ++rt) {
            short8 b_hi = *(const short8*)(vh + (size_t)rt * 16 * IN_F + k0);
            short8 b_lo = *(const short8*)(vl + (size_t)rt * 16 * IN_F + k0);
            acc[rt] = MFMA16(a_lo, b_hi, acc[rt]);
            acc[rt] = MFMA16(a_hi, b_lo, acc[rt]);
            acc[rt] = MFMA16(a_hi, b_hi, acc[rt]);
        }
    }

    // C/D layout: col = lane&15 (r within tile), row = quad*4 + reg (m)
    #pragma unroll
    for (int rt = 0; rt < 4; ++rt)
        #pragma unroll
        for (int rg = 0; rg < 4; ++rg)
            part[wv][quad * 4 + rg][rt * 16 + l15] = acc[rt][rg];
    __syncthreads();

    // Reduce 8 K-partials -> t, split to bf16 hi/lo. 1024 elems / 512 threads = 2 each.
    {
        const int e = tid * 2;
        const int m = e >> 6, r = e & 63;
        float s0 = 0.f, s1 = 0.f;
        #pragma unroll
        for (int w = 0; w < NWAVES; ++w) { s0 += part[w][m][r]; s1 += part[w][m][r + 1]; }
        short h0, l0, h1, l1;
        split2(s0, h0, l0); split2(s1, h1, l1);
        t_hi[m][r]     = (unsigned short)h0;  t_lo[m][r]     = (unsigned short)l0;
        t_hi[m][r + 1] = (unsigned short)h1;  t_lo[m][r + 1] = (unsigned short)l1;
    }
    __syncthreads();

    // ---------- Phase 2: out[m][o] = bias[o] + sum_r t[m][r]*U[o][r], wave owns 512 o ----------
    // A-frag from LDS t (16B aligned, padded stride 144B -> 2-way only). K=64 -> 2 k-steps.
    short8 ta_hi[2], ta_lo[2];
    #pragma unroll
    for (int ks = 0; ks < 2; ++ks) {
        ta_hi[ks] = *(const short8*)(&t_hi[l15][ks * 32 + quad * 8]);
        ta_lo[ks] = *(const short8*)(&t_lo[l15][ks * 32 + quad * 8]);
    }

    for (int nt = 0; nt < 32; ++nt) {
        const int o0 = wv * 512 + nt * 16;
        const int o  = o0 + l15;
        const float* Up = U + (size_t)o * RANK + quad * 8;
        const float bv = bias[o];
        float4v acc2 = {bv, bv, bv, bv};
        #pragma unroll
        for (int ks = 0; ks < 2; ++ks) {
            float4 u0 = *(const float4*)(Up + ks * 32);
            float4 u1 = *(const float4*)(Up + ks * 32 + 4);
            short8 u_hi, u_lo;
            split_f4x2(u0, u1, u_hi, u_lo);
            acc2 = MFMA16(ta_lo[ks], u_hi, acc2);
            acc2 = MFMA16(ta_hi[ks], u_lo, acc2);
            acc2 = MFMA16(ta_hi[ks], u_hi, acc2);
        }
        // C/D: col = o (lane&15), row = quad*4 + reg
        float* op = out + (size_t)(m0 + quad * 4) * OUT_F + o;
        op[0 * OUT_F] = acc2[0];
        op[1 * OUT_F] = acc2[1];
        op[2 * OUT_F] = acc2[2];
        op[3 * OUT_F] = acc2[3];
    }
}

// ---------------- Fallback (round-2 fp32 kernel) if ws is too small ----------------
__global__ __launch_bounds__(256, 2) void fallback_fp32(
    const float* __restrict__ x, const float* __restrict__ U,
    const float* __restrict__ V, const float* __restrict__ bias,
    float* __restrict__ out)
{
    __shared__ float v_lds[128][RANK];
    __shared__ float t_lds[8][RANK];
    const int tid = threadIdx.x, lane = tid & 63, wave = tid >> 6;
    const int m0 = blockIdx.x * 8;
    float acc0 = 0.f, acc1 = 0.f;
    const size_t row_base = (size_t)(m0 + wave * 2) * IN_F;
    for (int kt = 0; kt < IN_F; kt += 128) {
        const float4* Vg = (const float4*)(V + (size_t)kt * RANK);
        float4* Vs = (float4*)(&v_lds[0][0]);
        #pragma unroll
        for (int i = 0; i < 8; ++i) Vs[tid + 256 * i] = Vg[tid + 256 * i];
        __syncthreads();
        const float* xp = x + row_base + kt;
        #pragma unroll 8
        for (int k = 0; k < 128; k += 4) {
            float v0 = v_lds[k+0][lane], v1 = v_lds[k+1][lane];
            float v2 = v_lds[k+2][lane], v3 = v_lds[k+3][lane];
            float4 xa = *(const float4*)(xp + 0 * IN_F + k);
            float4 xb = *(const float4*)(xp + 1 * IN_F + k);
            acc0 += xa.x*v0 + xa.y*v1 + xa.z*v2 + xa.w*v3;
            acc1 += xb.x*v0 + xb.y*v1 + xb.z*v2 + xb.w*v3;
        }
        __syncthreads();
    }
    t_lds[wave*2+0][lane] = acc0;
    t_lds[wave*2+1][lane] = acc1;
    __syncthreads();
    for (int oc = 0; oc < OUT_F; oc += 1024) {
        const int o4 = oc + tid * 4;
        const float4 b4 = *(const float4*)(bias + o4);
        float4 a0=b4,a1=b4,a2=b4,a3=b4,a4=b4,a5=b4,a6=b4,a7=b4;
        const float* Up = U + (size_t)o4 * RANK;
        #pragma unroll 2
        for (int r0 = 0; r0 < RANK; r0 += 4) {
            const float4 u0 = *(const float4*)(Up + 0*RANK + r0);
            const float4 u1 = *(const float4*)(Up + 1*RANK + r0);
            const float4 u2 = *(const float4*)(Up + 2*RANK + r0);
            const float4 u3 = *(const float4*)(Up + 3*RANK + r0);
            #define P2_STEP(AM, MM) { \
                const float4 t4 = *(const float4*)(&t_lds[MM][r0]); \
                AM.x += t4.x*u0.x + t4.y*u0.y + t4.z*u0.z + t4.w*u0.w; \
                AM.y += t4.x*u1.x + t4.y*u1.y + t4.z*u1.z + t4.w*u1.w; \
                AM.z += t4.x*u2.x + t4.y*u2.y + t4.z*u2.z + t4.w*u2.w; \
                AM.w += t4.x*u3.x + t4.y*u3.y + t4.z*u3.z + t4.w*u3.w; }
            P2_STEP(a0,0) P2_STEP(a1,1) P2_STEP(a2,2) P2_STEP(a3,3)
            P2_STEP(a4,4) P2_STEP(a5,5) P2_STEP(a6,6) P2_STEP(a7,7)
            #undef P2_STEP
        }
        float* op = out + (size_t)m0 * OUT_F + o4;
        *(float4*)(op+0*OUT_F)=a0; *(float4*)(op+1*OUT_F)=a1;
        *(float4*)(op+2*OUT_F)=a2; *(float4*)(op+3*OUT_F)=a3;
        *(float4*)(op+4*OUT_F)=a4; *(float4*)(op+5*OUT_F)=a5;
        *(float4*)(op+6*OUT_F)=a6; *(float4*)(op+7*OUT_F)=a7;
    }
}

extern "C" void kernel_launch(void* const* d_in, const int* in_sizes, int n_in,
                              void* d_out, int out_size, void* d_ws, size_t ws_size,
                              hipStream_t stream) {
    const float* x    = (const float*)d_in[0];
    const float* U    = (const float*)d_in[1];
    const float* V    = (const float*)d_in[2];
    const float* bias = (const float*)d_in[3];
    float* out = (float*)d_out;

    const size_t need = (size_t)RANK * IN_F * sizeof(unsigned short) * 2;  // 1 MiB
    if (ws_size >= need) {
        unsigned short* vt_hi = (unsigned short*)d_ws;
        unsigned short* vt_lo = vt_hi + (size_t)RANK * IN_F;
        prep_v<<<dim3(256), dim3(256), 0, stream>>>(V, vt_hi, vt_lo);
        fused_lowrank_mfma<<<dim3(M_TOTAL / M_TILE), dim3(BLOCK), 0, stream>>>(
            x, U, bias, vt_hi, vt_lo, out);
    } else {
        fallback_fp32<<<dim3(M_TOTAL / 8), dim3(256), 0, stream>>>(x, U, V, bias, out);
    }
}